// Round 8
// baseline (32.114 us; speedup 1.0000x reference)
//
#include <hip/hip_runtime.h>

#define NP 64          // z_vals per ray
#define M  62          // w_mid count = searched cdf prefix length
#define RPB 4          // rays per block (one wave each)

// One DPP-scan step: x += dpp_shift(x). OOB/masked lanes contribute 0.
template<int CTRL, int RM>
__device__ __forceinline__ float dpp_add(float x) {
    const int y = __builtin_amdgcn_update_dpp(0, __float_as_int(x), CTRL, RM, 0xF, true);
    return x + __int_as_float(y);
}

// Full-lane DPP permute (quad_perm): all lanes written, old := src.
template<int CTRL>
__device__ __forceinline__ float dpp_perm(float x) {
    const int xi = __float_as_int(x);
    return __int_as_float(__builtin_amdgcn_update_dpp(xi, xi, CTRL, 0xF, 0xF, false));
}

__device__ __forceinline__ float rl_f(float x, int lane_imm) {
    return __int_as_float(__builtin_amdgcn_readlane(__float_as_int(x), lane_imm));
}

// Fully register-resident: zero __shared__, zero barriers.
__global__ __launch_bounds__(256) void nerf_fine_kernel(
    const float* __restrict__ rays_o,
    const float* __restrict__ rays_d,
    const float* __restrict__ weights,
    const float* __restrict__ z_vals,
    float* __restrict__ pts,        // [N,128,3]
    float* __restrict__ z_all_out,  // [N,128]
    int N)
{
    const int lane = threadIdx.x & 63;
    const int w    = threadIdx.x >> 6;
    const int ray  = blockIdx.x * RPB + w;
    if (ray >= N) return;

    // ---- loads: z[l], z[l+1], w[l+1] as coalesced streams ----
    const int lp1 = (lane < 63) ? (lane + 1) : 63;
    const float zv  = z_vals [(size_t)ray * NP + lane];
    const float zsh = z_vals [(size_t)ray * NP + lp1];
    const float wsh = weights[(size_t)ray * NP + lp1];

    const float rd0 = rays_d[(size_t)ray * 3 + 0];
    const float rd1 = rays_d[(size_t)ray * 3 + 1];
    const float rd2 = rays_d[(size_t)ray * 3 + 2];
    const float ro0 = rays_o[(size_t)ray * 3 + 0];
    const float ro1 = rays_o[(size_t)ray * 3 + 1];
    const float ro2 = rays_o[(size_t)ray * 3 + 2];

    // binsv_l = z_mid[l], valid l in [0,63)
    const float binsv = 0.5f * (zv + zsh);

    // w_mid[l] = weights[l+1] + EPS_W (l < 62), zeros above
    float v = (lane < M) ? (wsh + 1e-5f) : 0.0f;

    // ---- wave64 inclusive scan, pure DPP ----
    v = dpp_add<0x111, 0xF>(v);   // row_shr:1
    v = dpp_add<0x112, 0xF>(v);   // row_shr:2
    v = dpp_add<0x114, 0xF>(v);   // row_shr:4
    v = dpp_add<0x118, 0xF>(v);   // row_shr:8
    v = dpp_add<0x142, 0xA>(v);   // row_bcast:15 -> rows 1,3
    v = dpp_add<0x143, 0xC>(v);   // row_bcast:31 -> rows 2,3

    const float total = rl_f(v, 63);
    const float rtot  = __builtin_amdgcn_rcpf(total);
    const float cdfv  = v * rtot;       // lane l holds cdf[l+1], l in [0,62]

    // ---- searchsorted(cdf[0..61], u, 'right'), u = lane/63 ----
    // Iterations 0-3 probe compile-time midpoints {31},{15,47},{7,23,39,55},
    // {3..59}: fetch those 15 cdf entries via readlane (wave-uniform, all
    // independent) and run a cndmask tree. Iterations 4-5 stay bpermute.
    const float u = (float)lane * (1.0f / 63.0f);

    const float c31 = rl_f(cdfv, 30);
    const float c15 = rl_f(cdfv, 14), c47 = rl_f(cdfv, 46);
    const float c7  = rl_f(cdfv, 6),  c23 = rl_f(cdfv, 22);
    const float c39 = rl_f(cdfv, 38), c55 = rl_f(cdfv, 54);
    const float c3  = rl_f(cdfv, 2),  c11 = rl_f(cdfv, 10);
    const float c19 = rl_f(cdfv, 18), c27 = rl_f(cdfv, 26);
    const float c35 = rl_f(cdfv, 34), c43 = rl_f(cdfv, 42);
    const float c51 = rl_f(cdfv, 50), c59 = rl_f(cdfv, 58);

    const bool le0 = (c31 <= u);
    const bool le1 = ((le0 ? c47 : c15) <= u);
    const float cm2 = le0 ? (le1 ? c55 : c39) : (le1 ? c23 : c7);
    const bool le2 = (cm2 <= u);
    const float cm3 = le0 ? (le1 ? (le2 ? c59 : c51) : (le2 ? c43 : c35))
                          : (le1 ? (le2 ? c27 : c19) : (le2 ? c11 : c3));
    const bool le3 = (cm3 <= u);

    // state after 4 exact iterations: lo = Σ le_i * 2^(5-i), hi = min(lo+3, 62)
    int lo = ((int)le0 << 5) + ((int)le1 << 4) + ((int)le2 << 3) + ((int)le3 << 2);
    int hi = (lo + 3 < M) ? lo + 3 : M;

    // iteration 4 (always active: interval length >= 2 here)
    {
        const int mid = (lo + hi) >> 1;
        const float cv = __shfl(cdfv, mid - 1);      // mid >= 1 always
        const bool le  = (cv <= u);
        lo = le ? mid + 1 : lo;
        hi = le ? hi : mid;
    }
    // iteration 5 (act guard; mid==0 possible -> cdf[0]=0 <= u)
    {
        const int mid = (lo + hi) >> 1;
        float cv = __shfl(cdfv, mid - 1);
        cv = (mid == 0) ? -1.0f : cv;
        const bool le  = (cv <= u);
        const bool act = lo < hi;
        lo = (act &&  le) ? mid + 1 : lo;
        hi = (act && !le) ? mid     : hi;
    }
    const int above = lo;                            // [1,62]
    const int below = above - 1;                     // [0,61]

    const float ca = __shfl(cdfv, above - 1);        // cdf[above]
    float cb = __shfl(cdfv, below - 1);              // cdf[below]
    cb = (below == 0) ? 0.0f : cb;
    const float bb = __shfl(binsv, below);
    const float ba = __shfl(binsv, above);
    float denom = ca - cb;
    denom = (denom < 1e-5f) ? 1.0f : denom;
    const float t  = (u - cb) * __builtin_amdgcn_rcpf(denom);
    const float zs = fmaf(t, ba - bb, bb);           // sorted across lanes

    // ---- bitonic merge of two sorted 64-seqs, registers only ----
    // d=32/63 via shfl; d=16/8/4 via ds_swizzle xor; d=2/1 via DPP quad_perm.
    float lov, hiv;
    {
        const float t0 = __shfl_xor(zs, 63);         // zs[63-lane]
        lov = fminf(zv, t0);
        hiv = fmaxf(zv, t0);

        #define BSTAGE(D, PERML, PERMH)                                   \
        {                                                                 \
            const float pl_ = (PERML);                                    \
            const float ph_ = (PERMH);                                    \
            const bool up_ = (lane & (D)) != 0;                           \
            lov = up_ ? fmaxf(lov, pl_) : fminf(lov, pl_);                \
            hiv = up_ ? fmaxf(hiv, ph_) : fminf(hiv, ph_);                \
        }
        BSTAGE(32, __shfl_xor(lov, 32), __shfl_xor(hiv, 32))
        BSTAGE(16,
            __int_as_float(__builtin_amdgcn_ds_swizzle(__float_as_int(lov), 0x401F)),
            __int_as_float(__builtin_amdgcn_ds_swizzle(__float_as_int(hiv), 0x401F)))
        BSTAGE(8,
            __int_as_float(__builtin_amdgcn_ds_swizzle(__float_as_int(lov), 0x201F)),
            __int_as_float(__builtin_amdgcn_ds_swizzle(__float_as_int(hiv), 0x201F)))
        BSTAGE(4,
            __int_as_float(__builtin_amdgcn_ds_swizzle(__float_as_int(lov), 0x101F)),
            __int_as_float(__builtin_amdgcn_ds_swizzle(__float_as_int(hiv), 0x101F)))
        BSTAGE(2, dpp_perm<0x4E>(lov), dpp_perm<0x4E>(hiv))   // quad_perm(2,3,0,1)
        BSTAGE(1, dpp_perm<0xB1>(lov), dpp_perm<0xB1>(hiv))   // quad_perm(1,0,3,2)
        #undef BSTAGE
    }
    // lov = z_all[lane], hiv = z_all[64+lane]

    // ---- z_all: straight from registers, coalesced ----
    float* zo = z_all_out + (size_t)ray * 128;
    zo[lane]      = lov;
    zo[64 + lane] = hiv;

    // ---- pts: zero-shuffle epilogue; lane l owns rows l and 64+l ----
    float* pp = pts + (size_t)ray * 384 + 3 * lane;
    pp[0]   = fmaf(lov, rd0, ro0);
    pp[1]   = fmaf(lov, rd1, ro1);
    pp[2]   = fmaf(lov, rd2, ro2);
    pp[192] = fmaf(hiv, rd0, ro0);
    pp[193] = fmaf(hiv, rd1, ro1);
    pp[194] = fmaf(hiv, rd2, ro2);
}

extern "C" void kernel_launch(void* const* d_in, const int* in_sizes, int n_in,
                              void* d_out, int out_size, void* d_ws, size_t ws_size,
                              hipStream_t stream) {
    const float* rays_o  = (const float*)d_in[0];
    const float* rays_d  = (const float*)d_in[1];
    const float* weights = (const float*)d_in[2];
    const float* z_vals  = (const float*)d_in[3];

    const int N = in_sizes[2] / NP;                      // weights is [N, 64]
    float* pts   = (float*)d_out;                        // [N,128,3]
    float* z_all = (float*)d_out + (size_t)N * 128 * 3;  // [N,128]

    const int blocks = (N + RPB - 1) / RPB;
    nerf_fine_kernel<<<blocks, 256, 0, stream>>>(rays_o, rays_d, weights, z_vals,
                                                 pts, z_all, N);
}

// Round 9
// 31.891 us; speedup vs baseline: 1.0070x; 1.0070x over previous
//
#include <hip/hip_runtime.h>

#define NP 64          // z_vals per ray
#define M  62          // w_mid count = searched cdf prefix length
#define RPB 4          // rays per block (one wave each)

// One DPP-scan step: x += dpp_shift(x). OOB/masked lanes contribute 0.
template<int CTRL, int RM>
__device__ __forceinline__ float dpp_add(float x) {
    const int y = __builtin_amdgcn_update_dpp(0, __float_as_int(x), CTRL, RM, 0xF, true);
    return x + __int_as_float(y);
}

// Full-lane DPP permute (quad_perm): all lanes written, old := src.
template<int CTRL>
__device__ __forceinline__ float dpp_perm(float x) {
    const int xi = __float_as_int(x);
    return __int_as_float(__builtin_amdgcn_update_dpp(xi, xi, CTRL, 0xF, 0xF, false));
}

__device__ __forceinline__ float rl_f(float x, int lane_imm) {
    return __int_as_float(__builtin_amdgcn_readlane(__float_as_int(x), lane_imm));
}

// 12B store as ONE instruction: a wave of these at stride 12 covers a 768B
// span contiguously -> full-line requests from the intra-wave coalescer,
// instead of 3 stride-12 dword instructions each touching 6 lines partially.
typedef float vf3 __attribute__((ext_vector_type(3)));
__device__ __forceinline__ void store_f3(float* p, float a, float b, float c) {
    vf3 v; v.x = a; v.y = b; v.z = c;
    asm volatile("global_store_dwordx3 %0, %1, off" :: "v"(p), "v"(v) : "memory");
}

// Fully register-resident: zero __shared__, zero barriers.
__global__ __launch_bounds__(256) void nerf_fine_kernel(
    const float* __restrict__ rays_o,
    const float* __restrict__ rays_d,
    const float* __restrict__ weights,
    const float* __restrict__ z_vals,
    float* __restrict__ pts,        // [N,128,3]
    float* __restrict__ z_all_out,  // [N,128]
    int N)
{
    const int lane = threadIdx.x & 63;
    const int w    = threadIdx.x >> 6;
    const int ray  = blockIdx.x * RPB + w;
    if (ray >= N) return;

    // ---- loads: z[l], z[l+1], w[l+1] as coalesced streams ----
    const int lp1 = (lane < 63) ? (lane + 1) : 63;
    const float zv  = z_vals [(size_t)ray * NP + lane];
    const float zsh = z_vals [(size_t)ray * NP + lp1];
    const float wsh = weights[(size_t)ray * NP + lp1];

    const float rd0 = rays_d[(size_t)ray * 3 + 0];
    const float rd1 = rays_d[(size_t)ray * 3 + 1];
    const float rd2 = rays_d[(size_t)ray * 3 + 2];
    const float ro0 = rays_o[(size_t)ray * 3 + 0];
    const float ro1 = rays_o[(size_t)ray * 3 + 1];
    const float ro2 = rays_o[(size_t)ray * 3 + 2];

    // binsv_l = z_mid[l], valid l in [0,63)
    const float binsv = 0.5f * (zv + zsh);

    // w_mid[l] = weights[l+1] + EPS_W (l < 62), zeros above
    float v = (lane < M) ? (wsh + 1e-5f) : 0.0f;

    // ---- wave64 inclusive scan, pure DPP ----
    v = dpp_add<0x111, 0xF>(v);   // row_shr:1
    v = dpp_add<0x112, 0xF>(v);   // row_shr:2
    v = dpp_add<0x114, 0xF>(v);   // row_shr:4
    v = dpp_add<0x118, 0xF>(v);   // row_shr:8
    v = dpp_add<0x142, 0xA>(v);   // row_bcast:15 -> rows 1,3
    v = dpp_add<0x143, 0xC>(v);   // row_bcast:31 -> rows 2,3

    const float total = rl_f(v, 63);
    const float rtot  = __builtin_amdgcn_rcpf(total);
    const float cdfv  = v * rtot;       // lane l holds cdf[l+1], l in [0,62]

    // ---- searchsorted(cdf[0..61], u, 'right'), u = lane/63 ----
    // Rounds 0-3 probe compile-time midpoints via readlane tree; 4-5 bpermute.
    const float u = (float)lane * (1.0f / 63.0f);

    const float c31 = rl_f(cdfv, 30);
    const float c15 = rl_f(cdfv, 14), c47 = rl_f(cdfv, 46);
    const float c7  = rl_f(cdfv, 6),  c23 = rl_f(cdfv, 22);
    const float c39 = rl_f(cdfv, 38), c55 = rl_f(cdfv, 54);
    const float c3  = rl_f(cdfv, 2),  c11 = rl_f(cdfv, 10);
    const float c19 = rl_f(cdfv, 18), c27 = rl_f(cdfv, 26);
    const float c35 = rl_f(cdfv, 34), c43 = rl_f(cdfv, 42);
    const float c51 = rl_f(cdfv, 50), c59 = rl_f(cdfv, 58);

    const bool le0 = (c31 <= u);
    const bool le1 = ((le0 ? c47 : c15) <= u);
    const float cm2 = le0 ? (le1 ? c55 : c39) : (le1 ? c23 : c7);
    const bool le2 = (cm2 <= u);
    const float cm3 = le0 ? (le1 ? (le2 ? c59 : c51) : (le2 ? c43 : c35))
                          : (le1 ? (le2 ? c27 : c19) : (le2 ? c11 : c3));
    const bool le3 = (cm3 <= u);

    int lo = ((int)le0 << 5) + ((int)le1 << 4) + ((int)le2 << 3) + ((int)le3 << 2);
    int hi = (lo + 3 < M) ? lo + 3 : M;

    {   // iteration 4 (always active; mid >= 1)
        const int mid = (lo + hi) >> 1;
        const float cv = __shfl(cdfv, mid - 1);
        const bool le  = (cv <= u);
        lo = le ? mid + 1 : lo;
        hi = le ? hi : mid;
    }
    {   // iteration 5 (act guard; cdf[0]=0 <= u)
        const int mid = (lo + hi) >> 1;
        float cv = __shfl(cdfv, mid - 1);
        cv = (mid == 0) ? -1.0f : cv;
        const bool le  = (cv <= u);
        const bool act = lo < hi;
        lo = (act &&  le) ? mid + 1 : lo;
        hi = (act && !le) ? mid     : hi;
    }
    const int above = lo;                            // [1,62]
    const int below = above - 1;                     // [0,61]

    const float ca = __shfl(cdfv, above - 1);        // cdf[above]
    float cb = __shfl(cdfv, below - 1);              // cdf[below]
    cb = (below == 0) ? 0.0f : cb;
    const float bb = __shfl(binsv, below);
    const float ba = __shfl(binsv, above);
    float denom = ca - cb;
    denom = (denom < 1e-5f) ? 1.0f : denom;
    const float t  = (u - cb) * __builtin_amdgcn_rcpf(denom);
    const float zs = fmaf(t, ba - bb, bb);           // sorted across lanes

    // ---- bitonic merge of two sorted 64-seqs, registers only ----
    float lov, hiv;
    {
        const float t0 = __shfl_xor(zs, 63);         // zs[63-lane]
        lov = fminf(zv, t0);
        hiv = fmaxf(zv, t0);

        #define BSTAGE(D, PERML, PERMH)                                   \
        {                                                                 \
            const float pl_ = (PERML);                                    \
            const float ph_ = (PERMH);                                    \
            const bool up_ = (lane & (D)) != 0;                           \
            lov = up_ ? fmaxf(lov, pl_) : fminf(lov, pl_);                \
            hiv = up_ ? fmaxf(hiv, ph_) : fminf(hiv, ph_);                \
        }
        BSTAGE(32, __shfl_xor(lov, 32), __shfl_xor(hiv, 32))
        BSTAGE(16,
            __int_as_float(__builtin_amdgcn_ds_swizzle(__float_as_int(lov), 0x401F)),
            __int_as_float(__builtin_amdgcn_ds_swizzle(__float_as_int(hiv), 0x401F)))
        BSTAGE(8,
            __int_as_float(__builtin_amdgcn_ds_swizzle(__float_as_int(lov), 0x201F)),
            __int_as_float(__builtin_amdgcn_ds_swizzle(__float_as_int(hiv), 0x201F)))
        BSTAGE(4,
            __int_as_float(__builtin_amdgcn_ds_swizzle(__float_as_int(lov), 0x101F)),
            __int_as_float(__builtin_amdgcn_ds_swizzle(__float_as_int(hiv), 0x101F)))
        BSTAGE(2, dpp_perm<0x4E>(lov), dpp_perm<0x4E>(hiv))   // quad_perm(2,3,0,1)
        BSTAGE(1, dpp_perm<0xB1>(lov), dpp_perm<0xB1>(hiv))   // quad_perm(1,0,3,2)
        #undef BSTAGE
    }
    // lov = z_all[lane], hiv = z_all[64+lane]

    // ---- z_all: straight from registers, coalesced ----
    float* zo = z_all_out + (size_t)ray * 128;
    zo[lane]      = lov;
    zo[64 + lane] = hiv;

    // ---- pts: lane l owns rows l and 64+l; ONE dwordx3 per row ----
    float* pp = pts + (size_t)ray * 384 + 3 * lane;
    store_f3(pp,       fmaf(lov, rd0, ro0), fmaf(lov, rd1, ro1), fmaf(lov, rd2, ro2));
    store_f3(pp + 192, fmaf(hiv, rd0, ro0), fmaf(hiv, rd1, ro1), fmaf(hiv, rd2, ro2));
}

extern "C" void kernel_launch(void* const* d_in, const int* in_sizes, int n_in,
                              void* d_out, int out_size, void* d_ws, size_t ws_size,
                              hipStream_t stream) {
    const float* rays_o  = (const float*)d_in[0];
    const float* rays_d  = (const float*)d_in[1];
    const float* weights = (const float*)d_in[2];
    const float* z_vals  = (const float*)d_in[3];

    const int N = in_sizes[2] / NP;                      // weights is [N, 64]
    float* pts   = (float*)d_out;                        // [N,128,3]
    float* z_all = (float*)d_out + (size_t)N * 128 * 3;  // [N,128]

    const int blocks = (N + RPB - 1) / RPB;
    nerf_fine_kernel<<<blocks, 256, 0, stream>>>(rays_o, rays_d, weights, z_vals,
                                                 pts, z_all, N);
}